// Round 14
// baseline (464.811 us; speedup 1.0000x reference)
//
#include <hip/hip_runtime.h>

// LinearCrossAttention: B=16, N=4096, M=1024, C_in=C_cond=512, HIDDEN=512
#define KDIM 512

typedef __attribute__((ext_vector_type(8))) short bf16x8;
typedef __attribute__((ext_vector_type(4))) float f32x4;
typedef unsigned short u16;
typedef unsigned int u32;

static __device__ __forceinline__ u16 f2bf(float f) {
  u32 u = __builtin_bit_cast(u32, f);
  u32 r = u + 0x7fffu + ((u >> 16) & 1u);   // round-to-nearest-even
  return (u16)(r >> 16);
}
static __device__ __forceinline__ bf16x8 ld_frag(const u16* p) {
  uint2 lo = *(const uint2*)p;
  uint2 hi = *(const uint2*)(p + 4);
  uint4 u = make_uint4(lo.x, lo.y, hi.x, hi.y);
  return __builtin_bit_cast(bf16x8, u);
}

// ---------------------------------------------------------------------------
// prep: f32 -> bf16 (for Wkv), 8 elems/thread
// ---------------------------------------------------------------------------
__global__ __launch_bounds__(256) void cvt_f32_bf16(
    const float* __restrict__ src, u16* __restrict__ dst, int n8)
{
  int i = blockIdx.x * 256 + threadIdx.x;
  if (i >= n8) return;
  float4 a = *(const float4*)(src + (long)i * 8);
  float4 b = *(const float4*)(src + (long)i * 8 + 4);
  u32 w0 = (u32)f2bf(a.x) | ((u32)f2bf(a.y) << 16);
  u32 w1 = (u32)f2bf(a.z) | ((u32)f2bf(a.w) << 16);
  u32 w2 = (u32)f2bf(b.x) | ((u32)f2bf(b.y) << 16);
  u32 w3 = (u32)f2bf(b.z) | ((u32)f2bf(b.w) << 16);
  *(uint4*)(dst + (long)i * 8) = make_uint4(w0, w1, w2, w3);
}

// ---------------------------------------------------------------------------
// gemm_v: BM=512 / BN=64 / BK=64.  R8's proven mechanics (__syncthreads only,
// LDS double-buffer, depth-2 register prefetch, (512,2) register-clean,
// scalar 64B-exact epilogue) with HALF the K-steps: 8 steps x 1 barrier
// instead of 16 — halves the number of vmcnt(0) barrier drains (the measured
// fixed cost: ~5900 cy/step vs ~1500 cy useful at BK=32).  Enabled by >64KB
// static LDS (R8 ran 92KB): A dbuf 2x69.6KB + B dbuf 2x8.7KB = 153KB <= 160.
// 512 thr = 8 waves (8M); per-wave 64x64 out (acc = 64 AGPR).  ~180 unified
// regs -> no spill at (512,2).
// A: bf16 [*,512] row-major, staged linear pad-68 rows; thread t stages rows
// (t>>3)+64i, granule t&7 (8 lanes/row = 128B contiguous per row).
// B: f32 [512,ldn] streaming; transposed+cvt to Bsh[n][kpair] pad-34 u32
// rows; k-pair kp stored at position kp ^ ((n>>2 & 7)<<2)  (XOR keeps any
// aligned 4-pair group contiguous, so frag b64 reads stay vectorized; write
// banks <=2-way).
// ---------------------------------------------------------------------------
#define A0OFF 0
#define A1OFF 34816
#define B0OFF 69632
#define B1OFF 73984

#define V_LOADA(set, kt) { _Pragma("unroll") \
  for (int i_ = 0; i_ < 8; ++i_) \
    pa##set[i_] = *(const uint4*)(Ab + (long)(ar + i_ * 64) * KDIM + (kt) + ac * 8); }

#define V_LOADB(set, kt) { \
  pb##set##a = *(const float4*)(Bb + (long)((kt) + 2 * kp)     * ldn + nq * 4); \
  pb##set##b = *(const float4*)(Bb + (long)((kt) + 2 * kp + 1) * ldn + nq * 4); }

#define V_STAGE(aset, bset, ab, bb) { \
  _Pragma("unroll") for (int i_ = 0; i_ < 8; ++i_) \
    *(uint4*)&lds[(ab) + (ar + i_ * 64) * 68 + ac * 8] = pa##aset[i_]; \
  float f0_[4] = {pb##bset##a.x, pb##bset##a.y, pb##bset##a.z, pb##bset##a.w}; \
  float f1_[4] = {pb##bset##b.x, pb##bset##b.y, pb##bset##b.z, pb##bset##b.w}; \
  _Pragma("unroll") for (int j_ = 0; j_ < 4; ++j_) { \
    int n_ = nq * 4 + j_; \
    u32 w_ = (u32)f2bf(f0_[j_]) | ((u32)f2bf(f1_[j_]) << 16); \
    ((u32*)&lds[bb])[n_ * 34 + (kp ^ ((n_ >> 2 & 7) << 2))] = w_; } }

#define V_MFMA(ab, bb) { \
  _Pragma("unroll") for (int kk_ = 0; kk_ < 2; ++kk_) { \
    bf16x8 bfr_[4]; \
    _Pragma("unroll") for (int ni_ = 0; ni_ < 4; ++ni_) { \
      int n_ = ni_ * 16 + lrow; \
      bfr_[ni_] = ld_frag(&lds[(bb) + n_ * 68 + \
          (((kk_ * 16 + lkh * 4) ^ (((n_ >> 2) & 7) << 2)) * 2)]); } \
    __builtin_amdgcn_s_setprio(1); \
    _Pragma("unroll") for (int mi_ = 0; mi_ < 4; ++mi_) { \
      bf16x8 af_ = ld_frag(&lds[(ab) + (wv * 64 + mi_ * 16 + lrow) * 68 + kk_ * 32 + lkh * 8]); \
      _Pragma("unroll") for (int ni_ = 0; ni_ < 4; ++ni_) \
        acc[mi_][ni_] = __builtin_amdgcn_mfma_f32_16x16x32_bf16(af_, bfr_[ni_], acc[mi_][ni_], 0, 0, 0); } \
    __builtin_amdgcn_s_setprio(0); } }

template<bool OUT_BF16, bool BIAS, int MT, int NT>
__global__ __launch_bounds__(512, 2) void gemm_v(
    const u16* __restrict__ Ap, long a_bstride,
    const float* __restrict__ Bp, long b_bstride,
    void* __restrict__ Op, long o_bstride,
    const float* __restrict__ bias, int ldn)
{
  __shared__ u16 lds[78336];               // 153 KB: A 2x69.6KB + B 2x8.7KB

  const int d = blockIdx.x;                // mt innermost: B-slice sharers adjacent
  const int mt = d % MT;
  const int nt = (d / MT) % NT;
  const int b  = d / (MT * NT);
  const long mtile = (long)mt * 512;
  const long ntile = (long)nt * 64;
  const u16* Ab = Ap + (long)b * a_bstride + mtile * KDIM;
  const float* Bb = Bp + (long)b * b_bstride + ntile;

  const int t = threadIdx.x;
  const int lane = t & 63, wv = t >> 6;
  const int lrow = lane & 15, lkh = lane >> 4;

  // staging maps
  const int ar = t >> 3, ac = t & 7;       // A: rows ar+64i, 16B granule ac
  const int nq = t & 15;                   // B: 4-col group (64 cols)
  const int kp = t >> 4;                   // B: k-pair 0..31

  f32x4 acc[4][4] = {};
  uint4 pa0[8], pa1[8];
  float4 pb0a, pb0b, pb1a, pb1b;

  // ---- prologue: fill both reg sets, stage step 0 ----
  V_LOADA(0, 0)  V_LOADB(0, 0)
  V_LOADA(1, 64) V_LOADB(1, 64)
  V_STAGE(0, 0, A0OFF, B0OFF)
  __syncthreads();

  for (int s2 = 0; s2 < 4; ++s2) {         // 8 K-steps as even/odd pairs
    const int kt = s2 * 128;
    // even step: compute buf0; prefetch k+2 into set0; stage set1 -> buf1
    if (s2 < 3) { V_LOADA(0, kt + 128) V_LOADB(0, kt + 128) }
    V_MFMA(A0OFF, B0OFF)
    V_STAGE(1, 1, A1OFF, B1OFF)
    __syncthreads();
    // odd step: compute buf1; prefetch k+2 into set1; stage set0 -> buf0
    if (s2 < 3) { V_LOADA(1, kt + 192) V_LOADB(1, kt + 192) }
    V_MFMA(A1OFF, B1OFF)
    if (s2 < 3) {
      V_STAGE(0, 0, A0OFF, B0OFF)
      __syncthreads();
    }
  }

  // ---- epilogue: scalar stores, 16 lanes x 4B = 64B contiguous per instr ----
  #pragma unroll
  for (int mi = 0; mi < 4; ++mi) {
    #pragma unroll
    for (int r = 0; r < 4; ++r) {
      long gr = mtile + wv * 64 + mi * 16 + lkh * 4 + r;
      float bv = 0.0f;
      if constexpr (BIAS) bv = bias[gr];
      #pragma unroll
      for (int ni = 0; ni < 4; ++ni) {
        long gc = ntile + ni * 16 + lrow;
        float v = acc[mi][ni][r] + bv;
        if constexpr (OUT_BF16)
          ((u16*)Op)[(long)b * o_bstride + gr * ldn + gc] = f2bf(v);
        else
          ((float*)Op)[(long)b * o_bstride + gr * ldn + gc] = v;
      }
    }
  }
}

// ---------------------------------------------------------------------------
// K2: per (b,h): softmax over m of K rows, ctx[d][e] = sum_m Kexp[d][m]*V[e][m]
// ---------------------------------------------------------------------------
__global__ __launch_bounds__(256, 2) void softmax_context(
    const u16* __restrict__ kv, float* __restrict__ ctx)
{
  constexpr int LDE = 132;
  __shared__ float rowmax[64], rowinv[64];
  __shared__ u16 Ke[64 * LDE];
  __shared__ u16 Vs[64 * LDE];
  __shared__ float pr[64 * 68];

  const int bh = blockIdx.x;
  const u16* Kr = kv + (long)(bh >> 3) * (1024 * 1024) + (long)(bh & 7) * (64 * 1024);
  const u16* Vr = Kr + 512 * 1024;

  const int t = threadIdx.x;
  const int lane = t & 63, wv = t >> 6;
  const int lrow = lane & 15, lkh = lane >> 4;
  const int d4 = t >> 2, q4 = t & 3;

  {
    const u16* row = Kr + d4 * 1024 + q4 * 256;
    float mx = -3e38f;
    for (int i = 0; i < 256; i += 8) {
      uint4 v = *(const uint4*)(row + i);
      u32 ws[4] = {v.x, v.y, v.z, v.w};
      #pragma unroll
      for (int j = 0; j < 4; ++j) {
        mx = fmaxf(mx, __builtin_bit_cast(float, ws[j] << 16));
        mx = fmaxf(mx, __builtin_bit_cast(float, ws[j] & 0xffff0000u));
      }
    }
    mx = fmaxf(mx, __shfl_xor(mx, 1));
    mx = fmaxf(mx, __shfl_xor(mx, 2));
    float s = 0.f;
    for (int i = 0; i < 256; i += 8) {
      uint4 v = *(const uint4*)(row + i);
      u32 ws[4] = {v.x, v.y, v.z, v.w};
      #pragma unroll
      for (int j = 0; j < 4; ++j) {
        s += __expf(__builtin_bit_cast(float, ws[j] << 16) - mx);
        s += __expf(__builtin_bit_cast(float, ws[j] & 0xffff0000u) - mx);
      }
    }
    s += __shfl_xor(s, 1);
    s += __shfl_xor(s, 2);
    if (q4 == 0) { rowmax[d4] = mx; rowinv[d4] = 1.f / s; }
  }
  __syncthreads();

  f32x4 cacc[4][4] = {};

  for (int mc = 0; mc < 8; ++mc) {
    {
      int dd = t >> 2, j = t & 3;
      int m0 = mc * 128 + j * 32;
      float mx = rowmax[dd], inv = rowinv[dd];
      const u16* src = Kr + dd * 1024 + m0;
      u16* dst = &Ke[dd * LDE + j * 32];
      #pragma unroll
      for (int cq = 0; cq < 4; ++cq) {
        uint4 v = *(const uint4*)(src + cq * 8);
        u32 in[4] = {v.x, v.y, v.z, v.w};
        u32 out[4];
        #pragma unroll
        for (int j2 = 0; j2 < 4; ++j2) {
          float lo = __builtin_bit_cast(float, in[j2] << 16);
          float hif = __builtin_bit_cast(float, in[j2] & 0xffff0000u);
          out[j2] = (u32)f2bf(__expf(lo - mx) * inv) |
                    ((u32)f2bf(__expf(hif - mx) * inv) << 16);
        }
        *(uint2*)(dst + cq * 8)     = make_uint2(out[0], out[1]);
        *(uint2*)(dst + cq * 8 + 4) = make_uint2(out[2], out[3]);
      }
      const u16* vsrc = Vr + dd * 1024 + m0;
      u16* vdst = &Vs[dd * LDE + j * 32];
      #pragma unroll
      for (int cq = 0; cq < 4; ++cq) {
        uint4 v = *(const uint4*)(vsrc + cq * 8);
        *(uint2*)(vdst + cq * 8)     = make_uint2(v.x, v.y);
        *(uint2*)(vdst + cq * 8 + 4) = make_uint2(v.z, v.w);
      }
    }
    __syncthreads();
    bf16x8 ka[4], vb[4];
    #pragma unroll
    for (int mi = 0; mi < 4; ++mi)
      ka[mi] = ld_frag(&Ke[(mi * 16 + lrow) * LDE + wv * 32 + lkh * 8]);
    #pragma unroll
    for (int ni = 0; ni < 4; ++ni)
      vb[ni] = ld_frag(&Vs[(ni * 16 + lrow) * LDE + wv * 32 + lkh * 8]);
    #pragma unroll
    for (int mi = 0; mi < 4; ++mi)
      #pragma unroll
      for (int ni = 0; ni < 4; ++ni)
        cacc[mi][ni] = __builtin_amdgcn_mfma_f32_16x16x32_bf16(ka[mi], vb[ni], cacc[mi][ni], 0, 0, 0);
    __syncthreads();
  }

  for (int w = 0; w < 4; ++w) {
    if (wv == w) {
      #pragma unroll
      for (int mi = 0; mi < 4; ++mi)
        #pragma unroll
        for (int ni = 0; ni < 4; ++ni)
          #pragma unroll
          for (int r = 0; r < 4; ++r) {
            float* p = &pr[(mi * 16 + lkh * 4 + r) * 68 + (ni * 16 + lrow)];
            float v = cacc[mi][ni][r];
            if (w == 0) *p = v; else *p += v;
          }
    }
    __syncthreads();
  }
  float* cg = ctx + (long)bh * 4096;
  for (int i = 0; i < 16; ++i) {
    int o = t + i * 256;
    cg[o] = 0.125f * pr[(o >> 6) * 68 + (o & 63)];  // fold q-scale
  }
}

// ---------------------------------------------------------------------------
// K3a: U[b][o][h*64+d] = sum_e Wo[o][h*64+e] * ctx[b,h,d,e]
// ---------------------------------------------------------------------------
__global__ __launch_bounds__(256) void compose_u(
    const float* __restrict__ ctx, const float* __restrict__ Wo, u16* __restrict__ U)
{
  __shared__ float cs[16 * 64];
  const int bh = blockIdx.x, dq = blockIdx.y;
  const int b = bh >> 3, h = bh & 7;
  const int t = threadIdx.x;
  const float* cgrp = ctx + (long)bh * 4096 + dq * 16 * 64;
  for (int i = t; i < 1024; i += 256) cs[i] = cgrp[i];
  __syncthreads();
  #pragma unroll
  for (int rep = 0; rep < 2; ++rep) {
    int o = rep * 256 + t;
    const float* wrow = Wo + (long)o * 512 + h * 64;
    float acc[16] = {};
    for (int e = 0; e < 64; ++e) {
      float w = wrow[e];
      #pragma unroll
      for (int dd = 0; dd < 16; ++dd) acc[dd] += w * cs[dd * 64 + e];
    }
    u16* urow = U + (long)b * (512 * 512) + (long)o * 512 + h * 64 + dq * 16;
    #pragma unroll
    for (int dd = 0; dd < 16; ++dd) urow[dd] = f2bf(acc[dd]);
  }
}

// ---------------------------------------------------------------------------
extern "C" void kernel_launch(void* const* d_in, const int* in_sizes, int n_in,
                              void* d_out, int out_size, void* d_ws, size_t ws_size,
                              hipStream_t stream)
{
  const float* x   = (const float*)d_in[0];  // [16, 512, 4096]
  const float* c   = (const float*)d_in[1];  // [16, 512, 1024]
  const float* Wq  = (const float*)d_in[2];  // [512, 512]
  const float* Wkv = (const float*)d_in[3];  // [1024, 512]
  const float* Wo  = (const float*)d_in[4];  // [512, 512]
  const float* bo  = (const float*)d_in[5];  // [512]

  // workspace layout (52.4 MB total)
  char* ws = (char*)d_ws;
  u16*   kv   = (u16*)ws;                      // 16*1024*1024 bf16 = 33.5 MB
  float* ctx  = (float*)(ws + 33554432);       // 16*8*64*64 f32    =  2.1 MB
  u16*   U    = (u16*)(ws + 35651584);         // 16*512*512 bf16   =  8.4 MB
  u16*   Weff = (u16*)(ws + 44040192);         // 16*512*512 bf16   =  8.4 MB
  u16*   Wkvb = (u16*)(ws + 44040192);         // 1 MB, overlaps Weff: consumed by K1
                                               // BEFORE K3b writes Weff

  // K0: Wkv f32 -> bf16
  cvt_f32_bf16<<<dim3(256), 256, 0, stream>>>(Wkv, Wkvb, 65536);
  // K1: kv[b] = Wkv @ c[b]        MT=2, NT=16 -> 512 blocks
  gemm_v<true, false, 2, 16><<<dim3(2 * 16 * 16), 512, 0, stream>>>(
      Wkvb, 0, c, 512L * 1024, kv, 1024L * 1024, nullptr, 1024);
  // K2: softmax + context
  softmax_context<<<dim3(128), 256, 0, stream>>>(kv, ctx);
  // K3a: U = scale * Wo_h @ ctx_h^T
  compose_u<<<dim3(128, 4), 256, 0, stream>>>(ctx, Wo, U);
  // K3b: Weff[b] = U[b] @ Wq      MT=1, NT=8  -> 128 blocks
  gemm_v<true, false, 1, 8><<<dim3(1 * 8 * 16), 512, 0, stream>>>(
      U, 512L * 512, Wq, 0, Weff, 512L * 512, nullptr, 512);
  // K4: Y[b] = Weff[b] @ x[b] + bo   MT=1 (x read once), NT=64 -> 1024 blocks
  gemm_v<false, true, 1, 64><<<dim3(1 * 64 * 16), 512, 0, stream>>>(
      Weff, 512L * 512, x, 512L * 4096, d_out, 512L * 4096, bo, 4096);
}

// Round 15
// 255.640 us; speedup vs baseline: 1.8182x; 1.8182x over previous
//
#include <hip/hip_runtime.h>

// LinearCrossAttention: B=16, N=4096, M=1024, C_in=C_cond=512, HIDDEN=512
#define KDIM 512

typedef __attribute__((ext_vector_type(8))) short bf16x8;
typedef __attribute__((ext_vector_type(4))) float f32x4;
typedef unsigned short u16;
typedef unsigned int u32;

static __device__ __forceinline__ u16 f2bf(float f) {
  u32 u = __builtin_bit_cast(u32, f);
  u32 r = u + 0x7fffu + ((u >> 16) & 1u);   // round-to-nearest-even
  return (u16)(r >> 16);
}
static __device__ __forceinline__ bf16x8 ld_frag(const u16* p) {
  uint2 lo = *(const uint2*)p;
  uint2 hi = *(const uint2*)(p + 4);
  uint4 u = make_uint4(lo.x, lo.y, hi.x, hi.y);
  return __builtin_bit_cast(bf16x8, u);
}

// ---------------------------------------------------------------------------
// prep: f32 -> bf16 (for Wkv), 8 elems/thread
// ---------------------------------------------------------------------------
__global__ __launch_bounds__(256) void cvt_f32_bf16(
    const float* __restrict__ src, u16* __restrict__ dst, int n8)
{
  int i = blockIdx.x * 256 + threadIdx.x;
  if (i >= n8) return;
  float4 a = *(const float4*)(src + (long)i * 8);
  float4 b = *(const float4*)(src + (long)i * 8 + 4);
  u32 w0 = (u32)f2bf(a.x) | ((u32)f2bf(a.y) << 16);
  u32 w1 = (u32)f2bf(a.z) | ((u32)f2bf(a.w) << 16);
  u32 w2 = (u32)f2bf(b.x) | ((u32)f2bf(b.y) << 16);
  u32 w3 = (u32)f2bf(b.z) | ((u32)f2bf(b.w) << 16);
  *(uint4*)(dst + (long)i * 8) = make_uint4(w0, w1, w2, w3);
}

// ---------------------------------------------------------------------------
// gemm_w: R8's frame (BM=512/BN=128/BK=32, 512 thr = 8 waves 4Mx2N, per-wave
// 128x64, depth-2 B reg prefetch, __syncthreads only, scalar 64B-exact
// epilogue) MINUS the A-LDS round-trip.
//
// R8's step was LDS-pipe-bound: 136 KB/step/CU (A write 32K + A read 64K +
// B 40K) at ~85 B/cy ≈ 1700+ cy vs 310 cy MFMA.  A is a small L2-resident
// panel (Weff 512KB / Wkvb 1MB / U 512KB per batch) whose MFMA fragment IS
// its natural global layout: 16 rows x 64B fully-used lines per b128 load,
// L1/L2-hit.  So A-fragments load DIRECTLY from global inside the MFMA
// region (af[8] transient, ~32 VGPR peak, freed per-mi).  LDS carries only
// B (18.4 KB total) — LDS bytes/step drop 136 -> 40 KB.
// Registers: ~R8 - pa(32) + af(<=32 transient) ≈ 230 < 256 -> no spill.
// B path verbatim R8: reg-staged transpose+cvt, pad-36 u16 rows (read map
// verified conflict-free: banks 18n+4c all-distinct), XOR'd k-group writes.
// CLUST (K4): batch pinned to XCD (benign R2-form) so each XCD's L2 holds
// 2 Weff panels (1 MB) while blocks stream distinct x-slices.
// ---------------------------------------------------------------------------
#define B0OFF 0
#define B1OFF 4608

#define W_LOADB(set, kt) { \
  pb##set##a = *(const float4*)(Bb + (long)((kt) + krow)     * ldn + nq * 4); \
  pb##set##b = *(const float4*)(Bb + (long)((kt) + krow + 1) * ldn + nq * 4); }

#define W_STAGEB(set, bb) { \
  float f0_[4] = {pb##set##a.x, pb##set##a.y, pb##set##a.z, pb##set##a.w}; \
  float f1_[4] = {pb##set##b.x, pb##set##b.y, pb##set##b.z, pb##set##b.w}; \
  _Pragma("unroll") for (int j_ = 0; j_ < 4; ++j_) { \
    u32 w_ = (u32)f2bf(f0_[j_]) | ((u32)f2bf(f1_[j_]) << 16); \
    *(u32*)&lds[(bb) + (nq * 4 + j_) * 36 + krow] = w_; } }

#define W_MFMA(kt, bb) { \
  bf16x8 af_[8]; \
  _Pragma("unroll") for (int mi_ = 0; mi_ < 8; ++mi_) \
    af_[mi_] = *(const bf16x8*)(Aw + (long)(mi_ * 16) * KDIM + (kt)); \
  bf16x8 bfr_[4]; \
  _Pragma("unroll") for (int ni_ = 0; ni_ < 4; ++ni_) \
    bfr_[ni_] = ld_frag(&lds[(bb) + (wn * 64 + ni_ * 16 + lrow) * 36 + lkh * 8]); \
  __builtin_amdgcn_s_setprio(1); \
  _Pragma("unroll") for (int mi_ = 0; mi_ < 8; ++mi_) \
    _Pragma("unroll") for (int ni_ = 0; ni_ < 4; ++ni_) \
      acc[mi_][ni_] = __builtin_amdgcn_mfma_f32_16x16x32_bf16(af_[mi_], bfr_[ni_], acc[mi_][ni_], 0, 0, 0); \
  __builtin_amdgcn_s_setprio(0); }

template<bool OUT_BF16, bool BIAS, bool CLUST, int MT, int NT>
__global__ __launch_bounds__(512, 2) void gemm_w(
    const u16* __restrict__ Ap, long a_bstride,
    const float* __restrict__ Bp, long b_bstride,
    void* __restrict__ Op, long o_bstride,
    const float* __restrict__ bias, int ldn)
{
  __shared__ u16 lds[9216];                // 18.4 KB: B dbuf 2 x (128x36)

  int mt, nt, b;
  if constexpr (CLUST) {                   // K4: 512 blocks; batch -> XCD
    const int bx = blockIdx.x;
    b  = (bx & 7) | ((bx >> 8) << 3);      // xcd = batch-lo; bx>>8 = batch-hi
    nt = (bx >> 3) & 31;
    mt = 0;
  } else {
    const int d = blockIdx.x;              // mt innermost
    mt = d % MT;
    nt = (d / MT) % NT;
    b  = d / (MT * NT);
  }
  const long mtile = (long)mt * 512;
  const long ntile = (long)nt * 128;
  const u16* Ab = Ap + (long)b * a_bstride + mtile * KDIM;
  const float* Bb = Bp + (long)b * b_bstride + ntile;

  const int t = threadIdx.x;
  const int lane = t & 63, wv = t >> 6;
  const int wm = wv >> 1, wn = wv & 1;     // 4 x 2 wave grid
  const int lrow = lane & 15, lkh = lane >> 4;

  // per-lane A fragment base (direct-from-global; 16 lanes x 4 chunks = 16
  // fully-used 64B lines per b128-load issue, L2-resident panel)
  const u16* Aw = Ab + (long)(wm * 128 + lrow) * KDIM + lkh * 8;

  // B staging map (verbatim R8)
  const int nq = t & 31;                   // 4-col group (128 cols)
  const int hi = (t >> 8) & 1;
  const int kq = ((t >> 5) & 7) ^ ((t >> 2) & 7);  // XOR-spread k-group
  const int krow = kq * 4 + hi * 2;        // adjacent k-row pair

  f32x4 acc[8][4] = {};
  float4 pb0a, pb0b, pb1a, pb1b;

  // ---- prologue: fill both B reg sets, stage step 0 ----
  W_LOADB(0, 0)
  W_LOADB(1, 32)
  W_STAGEB(0, B0OFF)
  __syncthreads();

  for (int s2 = 0; s2 < 8; ++s2) {         // 16 K-steps as even/odd pairs
    const int kt = s2 * 64;
    // even step: prefetch B(s+2) into set0; compute buf0; stage set1 -> buf1
    if (s2 < 7) W_LOADB(0, kt + 64)
    W_MFMA(kt, B0OFF)
    W_STAGEB(1, B1OFF)
    __syncthreads();
    // odd step: prefetch B(s+2) into set1; compute buf1; stage set0 -> buf0
    if (s2 < 7) W_LOADB(1, kt + 96)
    W_MFMA(kt + 32, B1OFF)
    if (s2 < 7) {
      W_STAGEB(0, B0OFF)
      __syncthreads();
    }
  }

  // ---- epilogue: scalar stores, 16 lanes x 4B = 64B contiguous per instr ----
  #pragma unroll
  for (int mi = 0; mi < 8; ++mi) {
    #pragma unroll
    for (int r = 0; r < 4; ++r) {
      long gr = mtile + wm * 128 + mi * 16 + lkh * 4 + r;
      float bv = 0.0f;
      if constexpr (BIAS) bv = bias[gr];
      #pragma unroll
      for (int ni = 0; ni < 4; ++ni) {
        long gc = ntile + wn * 64 + ni * 16 + lrow;
        float v = acc[mi][ni][r] + bv;
        if constexpr (OUT_BF16)
          ((u16*)Op)[(long)b * o_bstride + gr * ldn + gc] = f2bf(v);
        else
          ((float*)Op)[(long)b * o_bstride + gr * ldn + gc] = v;
      }
    }
  }
}

// ---------------------------------------------------------------------------
// K2: per (b,h): softmax over m of K rows, ctx[d][e] = sum_m Kexp[d][m]*V[e][m]
// ---------------------------------------------------------------------------
__global__ __launch_bounds__(256, 2) void softmax_context(
    const u16* __restrict__ kv, float* __restrict__ ctx)
{
  constexpr int LDE = 132;
  __shared__ float rowmax[64], rowinv[64];
  __shared__ u16 Ke[64 * LDE];
  __shared__ u16 Vs[64 * LDE];
  __shared__ float pr[64 * 68];

  const int bh = blockIdx.x;
  const u16* Kr = kv + (long)(bh >> 3) * (1024 * 1024) + (long)(bh & 7) * (64 * 1024);
  const u16* Vr = Kr + 512 * 1024;

  const int t = threadIdx.x;
  const int lane = t & 63, wv = t >> 6;
  const int lrow = lane & 15, lkh = lane >> 4;
  const int d4 = t >> 2, q4 = t & 3;

  {
    const u16* row = Kr + d4 * 1024 + q4 * 256;
    float mx = -3e38f;
    for (int i = 0; i < 256; i += 8) {
      uint4 v = *(const uint4*)(row + i);
      u32 ws[4] = {v.x, v.y, v.z, v.w};
      #pragma unroll
      for (int j = 0; j < 4; ++j) {
        mx = fmaxf(mx, __builtin_bit_cast(float, ws[j] << 16));
        mx = fmaxf(mx, __builtin_bit_cast(float, ws[j] & 0xffff0000u));
      }
    }
    mx = fmaxf(mx, __shfl_xor(mx, 1));
    mx = fmaxf(mx, __shfl_xor(mx, 2));
    float s = 0.f;
    for (int i = 0; i < 256; i += 8) {
      uint4 v = *(const uint4*)(row + i);
      u32 ws[4] = {v.x, v.y, v.z, v.w};
      #pragma unroll
      for (int j = 0; j < 4; ++j) {
        s += __expf(__builtin_bit_cast(float, ws[j] << 16) - mx);
        s += __expf(__builtin_bit_cast(float, ws[j] & 0xffff0000u) - mx);
      }
    }
    s += __shfl_xor(s, 1);
    s += __shfl_xor(s, 2);
    if (q4 == 0) { rowmax[d4] = mx; rowinv[d4] = 1.f / s; }
  }
  __syncthreads();

  f32x4 cacc[4][4] = {};

  for (int mc = 0; mc < 8; ++mc) {
    {
      int dd = t >> 2, j = t & 3;
      int m0 = mc * 128 + j * 32;
      float mx = rowmax[dd], inv = rowinv[dd];
      const u16* src = Kr + dd * 1024 + m0;
      u16* dst = &Ke[dd * LDE + j * 32];
      #pragma unroll
      for (int cq = 0; cq < 4; ++cq) {
        uint4 v = *(const uint4*)(src + cq * 8);
        u32 in[4] = {v.x, v.y, v.z, v.w};
        u32 out[4];
        #pragma unroll
        for (int j2 = 0; j2 < 4; ++j2) {
          float lo = __builtin_bit_cast(float, in[j2] << 16);
          float hif = __builtin_bit_cast(float, in[j2] & 0xffff0000u);
          out[j2] = (u32)f2bf(__expf(lo - mx) * inv) |
                    ((u32)f2bf(__expf(hif - mx) * inv) << 16);
        }
        *(uint2*)(dst + cq * 8)     = make_uint2(out[0], out[1]);
        *(uint2*)(dst + cq * 8 + 4) = make_uint2(out[2], out[3]);
      }
      const u16* vsrc = Vr + dd * 1024 + m0;
      u16* vdst = &Vs[dd * LDE + j * 32];
      #pragma unroll
      for (int cq = 0; cq < 4; ++cq) {
        uint4 v = *(const uint4*)(vsrc + cq * 8);
        *(uint2*)(vdst + cq * 8)     = make_uint2(v.x, v.y);
        *(uint2*)(vdst + cq * 8 + 4) = make_uint2(v.z, v.w);
      }
    }
    __syncthreads();
    bf16x8 ka[4], vb[4];
    #pragma unroll
    for (int mi = 0; mi < 4; ++mi)
      ka[mi] = ld_frag(&Ke[(mi * 16 + lrow) * LDE + wv * 32 + lkh * 8]);
    #pragma unroll
    for (int ni = 0; ni < 4; ++ni)
      vb[ni] = ld_frag(&Vs[(ni * 16 + lrow) * LDE + wv * 32 + lkh * 8]);
    #pragma unroll
    for (int mi = 0; mi < 4; ++mi)
      #pragma unroll
      for (int ni = 0; ni < 4; ++ni)
        cacc[mi][ni] = __builtin_amdgcn_mfma_f32_16x16x32_bf16(ka[mi], vb[ni], cacc[mi][ni], 0, 0, 0);
    __syncthreads();
  }

  for (int w = 0; w < 4; ++w) {
    if (wv == w) {
      #pragma unroll
      for (int mi = 0; mi < 4; ++mi)
        #pragma unroll
        for (int ni = 0; ni < 4; ++ni)
          #pragma unroll
          for (int r = 0; r < 4; ++r) {
            float* p = &pr[(mi * 16 + lkh * 4 + r) * 68 + (ni * 16 + lrow)];
            float v = cacc[mi][ni][r];
            if (w == 0) *p = v; else *p += v;
          }
    }
    __syncthreads();
  }
  float* cg = ctx + (long)bh * 4096;
  for (int i = 0; i < 16; ++i) {
    int o = t + i * 256;
    cg[o] = 0.125f * pr[(o >> 6) * 68 + (o & 63)];  // fold q-scale
  }
}

// ---------------------------------------------------------------------------
// K3a: U[b][o][h*64+d] = sum_e Wo[o][h*64+e] * ctx[b,h,d,e]
// ---------------------------------------------------------------------------
__global__ __launch_bounds__(256) void compose_u(
    const float* __restrict__ ctx, const float* __restrict__ Wo, u16* __restrict__ U)
{
  __shared__ float cs[16 * 64];
  const int bh = blockIdx.x, dq = blockIdx.y;
  const int b = bh >> 3, h = bh & 7;
  const int t = threadIdx.x;
  const float* cgrp = ctx + (long)bh * 4096 + dq * 16 * 64;
  for (int i = t; i < 1024; i += 256) cs[i] = cgrp[i];
  __syncthreads();
  #pragma unroll
  for (int rep = 0; rep < 2; ++rep) {
    int o = rep * 256 + t;
    const float* wrow = Wo + (long)o * 512 + h * 64;
    float acc[16] = {};
    for (int e = 0; e < 64; ++e) {
      float w = wrow[e];
      #pragma unroll
      for (int dd = 0; dd < 16; ++dd) acc[dd] += w * cs[dd * 64 + e];
    }
    u16* urow = U + (long)b * (512 * 512) + (long)o * 512 + h * 64 + dq * 16;
    #pragma unroll
    for (int dd = 0; dd < 16; ++dd) urow[dd] = f2bf(acc[dd]);
  }
}

// ---------------------------------------------------------------------------
extern "C" void kernel_launch(void* const* d_in, const int* in_sizes, int n_in,
                              void* d_out, int out_size, void* d_ws, size_t ws_size,
                              hipStream_t stream)
{
  const float* x   = (const float*)d_in[0];  // [16, 512, 4096]
  const float* c   = (const float*)d_in[1];  // [16, 512, 1024]
  const float* Wq  = (const float*)d_in[2];  // [512, 512]
  const float* Wkv = (const float*)d_in[3];  // [1024, 512]
  const float* Wo  = (const float*)d_in[4];  // [512, 512]
  const float* bo  = (const float*)d_in[5];  // [512]

  // workspace layout (52.4 MB total)
  char* ws = (char*)d_ws;
  u16*   kv   = (u16*)ws;                      // 16*1024*1024 bf16 = 33.5 MB
  float* ctx  = (float*)(ws + 33554432);       // 16*8*64*64 f32    =  2.1 MB
  u16*   U    = (u16*)(ws + 35651584);         // 16*512*512 bf16   =  8.4 MB
  u16*   Weff = (u16*)(ws + 44040192);         // 16*512*512 bf16   =  8.4 MB
  u16*   Wkvb = (u16*)(ws + 44040192);         // 1 MB, overlaps Weff: consumed by K1
                                               // BEFORE K3b writes Weff

  // K0: Wkv f32 -> bf16
  cvt_f32_bf16<<<dim3(256), 256, 0, stream>>>(Wkv, Wkvb, 65536);
  // K1: kv[b] = Wkv @ c[b]        MT=2, NT=8  -> 256 blocks
  gemm_w<true, false, false, 2, 8><<<dim3(2 * 8 * 16), 512, 0, stream>>>(
      Wkvb, 0, c, 512L * 1024, kv, 1024L * 1024, nullptr, 1024);
  // K2: softmax + context
  softmax_context<<<dim3(128), 256, 0, stream>>>(kv, ctx);
  // K3a: U = scale * Wo_h @ ctx_h^T
  compose_u<<<dim3(128, 4), 256, 0, stream>>>(ctx, Wo, U);
  // K3b: Weff[b] = U[b] @ Wq      MT=1, NT=4  -> 64 blocks
  gemm_w<true, false, false, 1, 4><<<dim3(1 * 4 * 16), 512, 0, stream>>>(
      U, 512L * 512, Wq, 0, Weff, 512L * 512, nullptr, 512);
  // K4: Y[b] = Weff[b] @ x[b] + bo   batch->XCD clustered, 512 blocks
  gemm_w<false, true, true, 1, 32><<<dim3(512), 512, 0, stream>>>(
      Weff, 512L * 512, x, 512L * 4096, d_out, 512L * 4096, bo, 4096);
}

// Round 16
// 177.022 us; speedup vs baseline: 2.6257x; 1.4441x over previous
//
#include <hip/hip_runtime.h>

// LinearCrossAttention: B=16, N=4096, M=1024, C_in=C_cond=512, HIDDEN=512
#define KDIM 512

typedef __attribute__((ext_vector_type(8))) short bf16x8;
typedef __attribute__((ext_vector_type(4))) float f32x4;
typedef unsigned short u16;
typedef unsigned int u32;

static __device__ __forceinline__ u16 f2bf(float f) {
  u32 u = __builtin_bit_cast(u32, f);
  u32 r = u + 0x7fffu + ((u >> 16) & 1u);   // round-to-nearest-even
  return (u16)(r >> 16);
}
static __device__ __forceinline__ bf16x8 ld_frag(const u16* p) {
  uint2 lo = *(const uint2*)p;
  uint2 hi = *(const uint2*)(p + 4);
  uint4 u = make_uint4(lo.x, lo.y, hi.x, hi.y);
  return __builtin_bit_cast(bf16x8, u);
}

// ---------------------------------------------------------------------------
// prep: f32 -> bf16 (for Wkv), 8 elems/thread
// ---------------------------------------------------------------------------
__global__ __launch_bounds__(256) void cvt_f32_bf16(
    const float* __restrict__ src, u16* __restrict__ dst, int n8)
{
  int i = blockIdx.x * 256 + threadIdx.x;
  if (i >= n8) return;
  float4 a = *(const float4*)(src + (long)i * 8);
  float4 b = *(const float4*)(src + (long)i * 8 + 4);
  u32 w0 = (u32)f2bf(a.x) | ((u32)f2bf(a.y) << 16);
  u32 w1 = (u32)f2bf(a.z) | ((u32)f2bf(a.w) << 16);
  u32 w2 = (u32)f2bf(b.x) | ((u32)f2bf(b.y) << 16);
  u32 w3 = (u32)f2bf(b.z) | ((u32)f2bf(b.w) << 16);
  *(uint4*)(dst + (long)i * 8) = make_uint4(w0, w1, w2, w3);
}

// ---------------------------------------------------------------------------
// gemm_x: R8's gemm_p VERBATIM (best anchor: BM=512/BN=128/BK=32, 512 thr =
// 8 waves 4Mx2N, per-wave 128x64, LDS dbuf 92KB, depth-2 B + alternating A
// register prefetch, __launch_bounds__(512,2) — register-clean, WRITE exact)
// with ONE change, the fully-fenced raw barrier:
//
//   S_SYNC = sched_barrier(0); s_waitcnt lgkmcnt(0); sched_barrier(0);
//            s_barrier; sched_barrier(0)
//
// vs __syncthreads this drops ONLY the vmcnt(0) drain (hipcc emits
// "s_waitcnt vmcnt(0) lgkmcnt(0)" before every __syncthreads — the m97
// barrier-drain — force-draining the depth-2 prefetch each K-step).  The
// STAGE's vmcnt wait becomes dependency-counted: it waits only for its own
// 1-step-old loads (already complete); this step's prefetch loads stay in
// flight across the barrier (T4).
// R13 attempted this with a plain "memory"-clobber fence and raced; per
// guide gotcha #18, hipcc's machine scheduler hoists instructions past
// inline-asm s_waitcnt DESPITE the clobber — the documented fix is
// __builtin_amdgcn_sched_barrier(0) at each fence point, used here.
// Race ledger (per wave): buf-X frag ds_reads and buf-Y ds_writes complete
// under lgkmcnt(0) before its barrier; buf-X is only overwritten after the
// next barrier; in-flight global loads touch no LDS.  sched_barrier(0)
// pins all code motion across the fence points.
// ---------------------------------------------------------------------------
#define A0OFF 0
#define A1OFF 18432
#define B0OFF 36864
#define B1OFF 41472

#define P_LOADA(set, kt) { _Pragma("unroll") \
  for (int i_ = 0; i_ < 4; ++i_) \
    pa##set[i_] = *(const uint4*)(Ab + (long)(arow + i_ * 128) * KDIM + (kt) + ac * 8); }

#define P_LOADB(set, kt) { \
  pb##set##a = *(const float4*)(Bb + (long)((kt) + krow)     * ldn + nq * 4); \
  pb##set##b = *(const float4*)(Bb + (long)((kt) + krow + 1) * ldn + nq * 4); }

#define P_STAGE(aset, bset, ab, bb) { \
  _Pragma("unroll") for (int i_ = 0; i_ < 4; ++i_) { \
    u16* d_ = &lds[(ab) + (arow + i_ * 128) * 36 + ac * 8]; \
    *(uint2*)d_       = make_uint2(pa##aset[i_].x, pa##aset[i_].y); \
    *(uint2*)(d_ + 4) = make_uint2(pa##aset[i_].z, pa##aset[i_].w); } \
  float f0_[4] = {pb##bset##a.x, pb##bset##a.y, pb##bset##a.z, pb##bset##a.w}; \
  float f1_[4] = {pb##bset##b.x, pb##bset##b.y, pb##bset##b.z, pb##bset##b.w}; \
  _Pragma("unroll") for (int j_ = 0; j_ < 4; ++j_) { \
    u32 w_ = (u32)f2bf(f0_[j_]) | ((u32)f2bf(f1_[j_]) << 16); \
    *(u32*)&lds[(bb) + (nq * 4 + j_) * 36 + krow] = w_; } }

#define P_MFMA(ab, bb) { \
  bf16x8 bfr_[4]; \
  _Pragma("unroll") for (int ni_ = 0; ni_ < 4; ++ni_) \
    bfr_[ni_] = ld_frag(&lds[(bb) + (wn * 64 + ni_ * 16 + lrow) * 36 + lkh * 8]); \
  __builtin_amdgcn_s_setprio(1); \
  _Pragma("unroll") for (int mi_ = 0; mi_ < 8; ++mi_) { \
    bf16x8 af_ = ld_frag(&lds[(ab) + (wm * 128 + mi_ * 16 + lrow) * 36 + lkh * 8]); \
    _Pragma("unroll") for (int ni_ = 0; ni_ < 4; ++ni_) \
      acc[mi_][ni_] = __builtin_amdgcn_mfma_f32_16x16x32_bf16(af_, bfr_[ni_], acc[mi_][ni_], 0, 0, 0); } \
  __builtin_amdgcn_s_setprio(0); }

#define S_SYNC() { \
  __builtin_amdgcn_sched_barrier(0); \
  asm volatile("s_waitcnt lgkmcnt(0)" ::: "memory"); \
  __builtin_amdgcn_sched_barrier(0); \
  __builtin_amdgcn_s_barrier(); \
  __builtin_amdgcn_sched_barrier(0); }

template<bool OUT_BF16, bool BIAS, int MT, int NT>
__global__ __launch_bounds__(512, 2) void gemm_x(
    const u16* __restrict__ Ap, long a_bstride,
    const float* __restrict__ Bp, long b_bstride,
    void* __restrict__ Op, long o_bstride,
    const float* __restrict__ bias, int ldn)
{
  __shared__ u16 lds[46080];               // 92.16 KB: A dbuf 2x36.9 + B dbuf 2x9.2

  const int d = blockIdx.x;                // mt innermost: B-slice sharers adjacent
  const int mt = d % MT;
  const int nt = (d / MT) % NT;
  const int b  = d / (MT * NT);
  const long mtile = (long)mt * 512;
  const long ntile = (long)nt * 128;
  const u16* Ab = Ap + (long)b * a_bstride + mtile * KDIM;
  const float* Bb = Bp + (long)b * b_bstride + ntile;

  const int t = threadIdx.x;
  const int lane = t & 63, wv = t >> 6;
  const int wm = wv >> 1, wn = wv & 1;     // 4 x 2 wave grid
  const int lrow = lane & 15, lkh = lane >> 4;

  // staging maps (verbatim R8)
  const int arow = t >> 2, ac = t & 3;     // A: rows arow+128i, 16B granule ac
  const int nq = t & 31;                   // B: 4-col group (128 cols)
  const int hi = (t >> 8) & 1;
  const int kq = ((t >> 5) & 7) ^ ((t >> 2) & 7);  // XOR-spread 4-row group
  const int krow = kq * 4 + hi * 2;        // this thread's adjacent k-row pair

  f32x4 acc[8][4] = {};
  uint4 pa0[4], pa1[4];
  float4 pb0a, pb0b, pb1a, pb1b;

  // ---- prologue: fill both reg sets, stage step 0 ----
  P_LOADA(0, 0)  P_LOADB(0, 0)
  P_LOADA(1, 32) P_LOADB(1, 32)
  P_STAGE(0, 0, A0OFF, B0OFF)
  S_SYNC()

  for (int s2 = 0; s2 < 8; ++s2) {         // 16 K-steps as even/odd pairs
    const int kt = s2 * 64;
    // even step: compute buf0; prefetch k+2 into set0; stage set1 -> buf1
    if (s2 < 7) { P_LOADA(0, kt + 64) P_LOADB(0, kt + 64) }
    P_MFMA(A0OFF, B0OFF)
    P_STAGE(1, 1, A1OFF, B1OFF)
    S_SYNC()
    // odd step: compute buf1; prefetch k+2 into set1; stage set0 -> buf0
    if (s2 < 7) { P_LOADA(1, kt + 96) P_LOADB(1, kt + 96) }
    P_MFMA(A1OFF, B1OFF)
    if (s2 < 7) {
      P_STAGE(0, 0, A0OFF, B0OFF)
      S_SYNC()
    }
  }

  // ---- epilogue: scalar stores, 16 lanes x 4B = 64B contiguous per instr ----
  #pragma unroll
  for (int mi = 0; mi < 8; ++mi) {
    #pragma unroll
    for (int r = 0; r < 4; ++r) {
      long gr = mtile + wm * 128 + mi * 16 + lkh * 4 + r;
      float bv = 0.0f;
      if constexpr (BIAS) bv = bias[gr];
      #pragma unroll
      for (int ni = 0; ni < 4; ++ni) {
        long gc = ntile + wn * 64 + ni * 16 + lrow;
        float v = acc[mi][ni][r] + bv;
        if constexpr (OUT_BF16)
          ((u16*)Op)[(long)b * o_bstride + gr * ldn + gc] = f2bf(v);
        else
          ((float*)Op)[(long)b * o_bstride + gr * ldn + gc] = v;
      }
    }
  }
}

// ---------------------------------------------------------------------------
// K2: per (b,h): softmax over m of K rows, ctx[d][e] = sum_m Kexp[d][m]*V[e][m]
// ---------------------------------------------------------------------------
__global__ __launch_bounds__(256, 2) void softmax_context(
    const u16* __restrict__ kv, float* __restrict__ ctx)
{
  constexpr int LDE = 132;
  __shared__ float rowmax[64], rowinv[64];
  __shared__ u16 Ke[64 * LDE];
  __shared__ u16 Vs[64 * LDE];
  __shared__ float pr[64 * 68];

  const int bh = blockIdx.x;
  const u16* Kr = kv + (long)(bh >> 3) * (1024 * 1024) + (long)(bh & 7) * (64 * 1024);
  const u16* Vr = Kr + 512 * 1024;

  const int t = threadIdx.x;
  const int lane = t & 63, wv = t >> 6;
  const int lrow = lane & 15, lkh = lane >> 4;
  const int d4 = t >> 2, q4 = t & 3;

  {
    const u16* row = Kr + d4 * 1024 + q4 * 256;
    float mx = -3e38f;
    for (int i = 0; i < 256; i += 8) {
      uint4 v = *(const uint4*)(row + i);
      u32 ws[4] = {v.x, v.y, v.z, v.w};
      #pragma unroll
      for (int j = 0; j < 4; ++j) {
        mx = fmaxf(mx, __builtin_bit_cast(float, ws[j] << 16));
        mx = fmaxf(mx, __builtin_bit_cast(float, ws[j] & 0xffff0000u));
      }
    }
    mx = fmaxf(mx, __shfl_xor(mx, 1));
    mx = fmaxf(mx, __shfl_xor(mx, 2));
    float s = 0.f;
    for (int i = 0; i < 256; i += 8) {
      uint4 v = *(const uint4*)(row + i);
      u32 ws[4] = {v.x, v.y, v.z, v.w};
      #pragma unroll
      for (int j = 0; j < 4; ++j) {
        s += __expf(__builtin_bit_cast(float, ws[j] << 16) - mx);
        s += __expf(__builtin_bit_cast(float, ws[j] & 0xffff0000u) - mx);
      }
    }
    s += __shfl_xor(s, 1);
    s += __shfl_xor(s, 2);
    if (q4 == 0) { rowmax[d4] = mx; rowinv[d4] = 1.f / s; }
  }
  __syncthreads();

  f32x4 cacc[4][4] = {};

  for (int mc = 0; mc < 8; ++mc) {
    {
      int dd = t >> 2, j = t & 3;
      int m0 = mc * 128 + j * 32;
      float mx = rowmax[dd], inv = rowinv[dd];
      const u16* src = Kr + dd * 1024 + m0;
      u16* dst = &Ke[dd * LDE + j * 32];
      #pragma unroll
      for (int cq = 0; cq < 4; ++cq) {
        uint4 v = *(const uint4*)(src + cq * 8);
        u32 in[4] = {v.x, v.y, v.z, v.w};
        u32 out[4];
        #pragma unroll
        for (int j2 = 0; j2 < 4; ++j2) {
          float lo = __builtin_bit_cast(float, in[j2] << 16);
          float hif = __builtin_bit_cast(float, in[j2] & 0xffff0000u);
          out[j2] = (u32)f2bf(__expf(lo - mx) * inv) |
                    ((u32)f2bf(__expf(hif - mx) * inv) << 16);
        }
        *(uint2*)(dst + cq * 8)     = make_uint2(out[0], out[1]);
        *(uint2*)(dst + cq * 8 + 4) = make_uint2(out[2], out[3]);
      }
      const u16* vsrc = Vr + dd * 1024 + m0;
      u16* vdst = &Vs[dd * LDE + j * 32];
      #pragma unroll
      for (int cq = 0; cq < 4; ++cq) {
        uint4 v = *(const uint4*)(vsrc + cq * 8);
        *(uint2*)(vdst + cq * 8)     = make_uint2(v.x, v.y);
        *(uint2*)(vdst + cq * 8 + 4) = make_uint2(v.z, v.w);
      }
    }
    __syncthreads();
    bf16x8 ka[4], vb[4];
    #pragma unroll
    for (int mi = 0; mi < 4; ++mi)
      ka[mi] = ld_frag(&Ke[(mi * 16 + lrow) * LDE + wv * 32 + lkh * 8]);
    #pragma unroll
    for (int ni = 0; ni < 4; ++ni)
      vb[ni] = ld_frag(&Vs[(ni * 16 + lrow) * LDE + wv * 32 + lkh * 8]);
    #pragma unroll
    for (int mi = 0; mi < 4; ++mi)
      #pragma unroll
      for (int ni = 0; ni < 4; ++ni)
        cacc[mi][ni] = __builtin_amdgcn_mfma_f32_16x16x32_bf16(ka[mi], vb[ni], cacc[mi][ni], 0, 0, 0);
    __syncthreads();
  }

  for (int w = 0; w < 4; ++w) {
    if (wv == w) {
      #pragma unroll
      for (int mi = 0; mi < 4; ++mi)
        #pragma unroll
        for (int ni = 0; ni < 4; ++ni)
          #pragma unroll
          for (int r = 0; r < 4; ++r) {
            float* p = &pr[(mi * 16 + lkh * 4 + r) * 68 + (ni * 16 + lrow)];
            float v = cacc[mi][ni][r];
            if (w == 0) *p = v; else *p += v;
          }
    }
    __syncthreads();
  }
  float* cg = ctx + (long)bh * 4096;
  for (int i = 0; i < 16; ++i) {
    int o = t + i * 256;
    cg[o] = 0.125f * pr[(o >> 6) * 68 + (o & 63)];  // fold q-scale
  }
}

// ---------------------------------------------------------------------------
// K3a: U[b][o][h*64+d] = sum_e Wo[o][h*64+e] * ctx[b,h,d,e]
// ---------------------------------------------------------------------------
__global__ __launch_bounds__(256) void compose_u(
    const float* __restrict__ ctx, const float* __restrict__ Wo, u16* __restrict__ U)
{
  __shared__ float cs[16 * 64];
  const int bh = blockIdx.x, dq = blockIdx.y;
  const int b = bh >> 3, h = bh & 7;
  const int t = threadIdx.x;
  const float* cgrp = ctx + (long)bh * 4096 + dq * 16 * 64;
  for (int i = t; i < 1024; i += 256) cs[i] = cgrp[i];
  __syncthreads();
  #pragma unroll
  for (int rep = 0; rep < 2; ++rep) {
    int o = rep * 256 + t;
    const float* wrow = Wo + (long)o * 512 + h * 64;
    float acc[16] = {};
    for (int e = 0; e < 64; ++e) {
      float w = wrow[e];
      #pragma unroll
      for (int dd = 0; dd < 16; ++dd) acc[dd] += w * cs[dd * 64 + e];
    }
    u16* urow = U + (long)b * (512 * 512) + (long)o * 512 + h * 64 + dq * 16;
    #pragma unroll
    for (int dd = 0; dd < 16; ++dd) urow[dd] = f2bf(acc[dd]);
  }
}

// ---------------------------------------------------------------------------
extern "C" void kernel_launch(void* const* d_in, const int* in_sizes, int n_in,
                              void* d_out, int out_size, void* d_ws, size_t ws_size,
                              hipStream_t stream)
{
  const float* x   = (const float*)d_in[0];  // [16, 512, 4096]
  const float* c   = (const float*)d_in[1];  // [16, 512, 1024]
  const float* Wq  = (const float*)d_in[2];  // [512, 512]
  const float* Wkv = (const float*)d_in[3];  // [1024, 512]
  const float* Wo  = (const float*)d_in[4];  // [512, 512]
  const float* bo  = (const float*)d_in[5];  // [512]

  // workspace layout (52.4 MB total)
  char* ws = (char*)d_ws;
  u16*   kv   = (u16*)ws;                      // 16*1024*1024 bf16 = 33.5 MB
  float* ctx  = (float*)(ws + 33554432);       // 16*8*64*64 f32    =  2.1 MB
  u16*   U    = (u16*)(ws + 35651584);         // 16*512*512 bf16   =  8.4 MB
  u16*   Weff = (u16*)(ws + 44040192);         // 16*512*512 bf16   =  8.4 MB
  u16*   Wkvb = (u16*)(ws + 44040192);         // 1 MB, overlaps Weff: consumed by K1
                                               // BEFORE K3b writes Weff

  // K0: Wkv f32 -> bf16
  cvt_f32_bf16<<<dim3(256), 256, 0, stream>>>(Wkv, Wkvb, 65536);
  // K1: kv[b] = Wkv @ c[b]        MT=2, NT=8  -> 256 blocks
  gemm_x<true, false, 2, 8><<<dim3(2 * 8 * 16), 512, 0, stream>>>(
      Wkvb, 0, c, 512L * 1024, kv, 1024L * 1024, nullptr, 1024);
  // K2: softmax + context
  softmax_context<<<dim3(128), 256, 0, stream>>>(kv, ctx);
  // K3a: U = scale * Wo_h @ ctx_h^T
  compose_u<<<dim3(128, 4), 256, 0, stream>>>(ctx, Wo, U);
  // K3b: Weff[b] = U[b] @ Wq      MT=1, NT=4  -> 64 blocks
  gemm_x<true, false, 1, 4><<<dim3(1 * 4 * 16), 512, 0, stream>>>(
      U, 512L * 512, Wq, 0, Weff, 512L * 512, nullptr, 512);
  // K4: Y[b] = Weff[b] @ x[b] + bo   MT=1 (x read once), NT=32 -> 512 blocks
  gemm_x<false, true, 1, 32><<<dim3(1 * 32 * 16), 512, 0, stream>>>(
      Weff, 512L * 512, x, 512L * 4096, d_out, 512L * 4096, bo, 4096);
}